// Round 5
// baseline (641.867 us; speedup 1.0000x reference)
//
#include <hip/hip_runtime.h>
#include <float.h>
#include <limits.h>

// Codebook / VQ: x [65536][256] fp32, codes [1024][256] fp32
// out: quantized [65536][256] fp32, then indices [65536] as fp32 values.
// Fast fp32 GEMM argmin for all rows; near-tie rows (fp32 top-2 gap < EPS) are
// re-scored exactly in fp64, then: among codes within DELTA of the exact min,
// emit the SMALLEST index (replicates np-fp32 ulp-collision + argmin
// first-occurrence semantics, per the round-4 marker experiment).
#define D     256
#define C     1024
#define TM    128
#define TC    128
#define KT    32
#define LDP   132
#define EPS   0.02f     // flag threshold on fp32-measured top-2 gap
#define DELTA 1.0e-4    // np ulp-collision window on exact fp64 distances

__global__ void prep_cnorm(const float* __restrict__ codes, float* __restrict__ cnorm,
                           int* __restrict__ count) {
    if (blockIdx.x == 0 && threadIdx.x == 0) *count = 0;
    int wave = (blockIdx.x * blockDim.x + threadIdx.x) >> 6;   // one wave per code row
    int lane = threadIdx.x & 63;
    if (wave >= C) return;
    float4 v = ((const float4*)(codes + (size_t)wave * D))[lane];
    float s = v.x * v.x + v.y * v.y + v.z * v.z + v.w * v.w;
    #pragma unroll
    for (int off = 32; off >= 1; off >>= 1) s += __shfl_xor(s, off, 64);
    if (lane == 0) cnorm[wave] = s;
}

__global__ __launch_bounds__(256, 2)
void codebook_main(const float* __restrict__ x, const float* __restrict__ codes,
                   const float* __restrict__ cnorm,
                   float* __restrict__ out_q, float* __restrict__ out_i,
                   int* __restrict__ count, int* __restrict__ rowlist) {
    __shared__ float xs[KT][LDP];
    __shared__ float cs[KT][LDP];
    __shared__ int   si[TM * 16];
    __shared__ int   win[TM];

    const int tid  = threadIdx.x;
    const int tx   = tid & 15;
    const int ty   = tid >> 4;
    const int row0 = blockIdx.x * TM;

    float m1[8], m2[8];
    int   i1[8];
    #pragma unroll
    for (int i = 0; i < 8; ++i) { m1[i] = FLT_MAX; m2[i] = FLT_MAX; i1[i] = 0; }

    for (int tile = 0; tile < C / TC; ++tile) {
        float acc[8][8];
        #pragma unroll
        for (int i = 0; i < 8; ++i)
            #pragma unroll
            for (int j = 0; j < 8; ++j) acc[i][j] = 0.0f;

        for (int kc = 0; kc < D / KT; ++kc) {
            const int k0 = kc * KT;
            __syncthreads();
            #pragma unroll
            for (int p = 0; p < 4; ++p) {
                int flat = p * 256 + tid;
                int r    = flat >> 3;
                int q    = flat & 7;
                float4 v = *(const float4*)(x + (size_t)(row0 + r) * D + k0 + 4 * q);
                xs[4*q+0][r] = v.x; xs[4*q+1][r] = v.y; xs[4*q+2][r] = v.z; xs[4*q+3][r] = v.w;
                float4 w = *(const float4*)(codes + (size_t)(tile * TC + r) * D + k0 + 4 * q);
                cs[4*q+0][r] = w.x; cs[4*q+1][r] = w.y; cs[4*q+2][r] = w.z; cs[4*q+3][r] = w.w;
            }
            __syncthreads();

            #pragma unroll 4
            for (int kk = 0; kk < KT; ++kk) {
                float a[8], b[8];
                *(float4*)&a[0] = *(const float4*)&xs[kk][ty * 8];
                *(float4*)&a[4] = *(const float4*)&xs[kk][ty * 8 + 4];
                *(float4*)&b[0] = *(const float4*)&cs[kk][tx * 8];
                *(float4*)&b[4] = *(const float4*)&cs[kk][tx * 8 + 4];
                #pragma unroll
                for (int i = 0; i < 8; ++i)
                    #pragma unroll
                    for (int j = 0; j < 8; ++j)
                        acc[i][j] = fmaf(a[i], b[j], acc[i][j]);
            }
        }

        float cn[8];
        #pragma unroll
        for (int j = 0; j < 8; ++j) cn[j] = cnorm[tile * TC + tx * 8 + j];
        #pragma unroll
        for (int i = 0; i < 8; ++i) {
            #pragma unroll
            for (int j = 0; j < 8; ++j) {
                float dd = fmaf(-2.0f, acc[i][j], cn[j]);
                int code = tile * TC + tx * 8 + j;
                if (dd < m1[i]) { m2[i] = m1[i]; m1[i] = dd; i1[i] = code; }
                else if (dd < m2[i]) { m2[i] = dd; }
            }
        }
    }

    float* fm1 = &xs[0][0];
    float* fm2 = &cs[0][0];
    __syncthreads();
    #pragma unroll
    for (int i = 0; i < 8; ++i) {
        int row = ty * 8 + i;
        fm1[row * 16 + tx] = m1[i];
        fm2[row * 16 + tx] = m2[i];
        si [row * 16 + tx] = i1[i];
    }
    __syncthreads();
    if (tid < TM) {
        float b1 = FLT_MAX, b2 = FLT_MAX;
        int   bi = 0x7fffffff;
        #pragma unroll
        for (int t = 0; t < 16; ++t) {
            float v1 = fm1[tid * 16 + t];
            float v2 = fm2[tid * 16 + t];
            int   ii = si [tid * 16 + t];
            if (v1 < b1 || (v1 == b1 && ii < bi)) {
                b2 = fminf(b1, v2); b1 = v1; bi = ii;
            } else {
                b2 = fminf(b2, v1);
            }
        }
        win[tid] = bi;
        out_i[row0 + tid] = (float)bi;
        if (b2 - b1 < EPS) {                 // near-tie: np rounding could differ
            int slot = atomicAdd(count, 1);
            rowlist[slot] = row0 + tid;
        }
    }
    __syncthreads();

    #pragma unroll
    for (int p = 0; p < 32; ++p) {
        int flat = p * 256 + tid;
        int r    = flat >> 6;
        int f4   = flat & 63;
        float4 v = *(const float4*)(codes + (size_t)win[r] * D + 4 * f4);
        *(float4*)(out_q + (size_t)(row0 + r) * D + 4 * f4) = v;
    }
}

// Exact fp64 rescore of flagged rows; pick smallest index within DELTA of min.
__global__ __launch_bounds__(256)
void rescue_exact(const float* __restrict__ x, const float* __restrict__ codes,
                  const int* __restrict__ count, const int* __restrict__ rowlist,
                  float* __restrict__ out_q, float* __restrict__ out_i) {
    __shared__ float  xrow[D];
    __shared__ double dbuf[C];
    __shared__ double rmin[256];
    __shared__ int    ridx[256];
    const int t = threadIdx.x;
    const int n = *count;
    for (int idx = blockIdx.x; idx < n; idx += gridDim.x) {
        const int row = rowlist[idx];
        __syncthreads();
        xrow[t] = x[(size_t)row * D + t];
        __syncthreads();

        // exact fp64 distance for codes 4t..4t+3
        double lmin = 1e300;
        #pragma unroll
        for (int j = 0; j < 4; ++j) {
            const int c = 4 * t + j;
            const float* cp = codes + (size_t)c * D;
            double s = 0.0;
            for (int k = 0; k < D; k += 4) {
                float4 cv = *(const float4*)(cp + k);
                double d0 = (double)xrow[k+0] - (double)cv.x;
                double d1 = (double)xrow[k+1] - (double)cv.y;
                double d2 = (double)xrow[k+2] - (double)cv.z;
                double d3 = (double)xrow[k+3] - (double)cv.w;
                s += d0*d0 + d1*d1 + d2*d2 + d3*d3;
            }
            dbuf[c] = s;
            lmin = fmin(lmin, s);
        }
        rmin[t] = lmin;
        __syncthreads();
        for (int sft = 128; sft > 0; sft >>= 1) {
            if (t < sft) rmin[t] = fmin(rmin[t], rmin[t + sft]);
            __syncthreads();
        }
        const double dstar = rmin[0];

        // smallest index within the np ulp-collision window
        int lidx = INT_MAX;
        #pragma unroll
        for (int j = 0; j < 4; ++j) {
            const int c = 4 * t + j;
            if (dbuf[c] < dstar + DELTA && c < lidx) lidx = c;
        }
        ridx[t] = lidx;
        __syncthreads();
        for (int sft = 128; sft > 0; sft >>= 1) {
            if (t < sft) ridx[t] = min(ridx[t], ridx[t + sft]);
            __syncthreads();
        }
        const int winc = ridx[0];

        if (t == 0) out_i[row] = (float)winc;
        if (t < 64) {
            float4 cv = ((const float4*)(codes + (size_t)winc * D))[t];
            ((float4*)(out_q + (size_t)row * D))[t] = cv;
        }
        __syncthreads();
    }
}

extern "C" void kernel_launch(void* const* d_in, const int* in_sizes, int n_in,
                              void* d_out, int out_size, void* d_ws, size_t ws_size,
                              hipStream_t stream) {
    const float* x     = (const float*)d_in[0];
    const float* codes = (const float*)d_in[1];
    const int N = in_sizes[0] / D;                 // 65536

    float* cnorm   = (float*)d_ws;                 // C floats
    int*   count   = (int*)(cnorm + C);            // 1 int
    int*   rowlist = count + 1;                    // up to N ints
    float* out_q   = (float*)d_out;
    float* out_i   = out_q + (size_t)N * D;

    prep_cnorm<<<C / 4, 256, 0, stream>>>(codes, cnorm, count);
    codebook_main<<<N / TM, 256, 0, stream>>>(x, codes, cnorm, out_q, out_i, count, rowlist);
    rescue_exact<<<512, 256, 0, stream>>>(x, codes, count, rowlist, out_q, out_i);
}

// Round 7
// 384.845 us; speedup vs baseline: 1.6679x; 1.6679x over previous
//
#include <hip/hip_runtime.h>
#include <float.h>
#include <limits.h>

// Codebook / VQ: x [65536][256] fp32, codes [1024][256] fp32
// out: quantized [65536][256] fp32, then indices [65536] as fp32 values.
// Tiered: fp16 MFMA GEMM argmin (all rows) -> fp32 rescue (gap<EPS1 rows)
//        -> fp64+DELTA smallest-index rescue (gap<EPS2 rows, proven round 5).
#define D     256
#define C     1024
#define EPS1  0.3f      // fp16-MFMA gap flag (worst-case fp16 dist err ~0.1)
#define EPS2  0.02f     // fp32 gap flag (proven)
#define DELTA 1.0e-4    // np ulp-collision window on exact fp64 distances
#define BR    16        // rows per batch in fp32 rescue

typedef _Float16 half8 __attribute__((ext_vector_type(8)));
typedef _Float16 half4_t __attribute__((ext_vector_type(4)));
typedef float v4f __attribute__((ext_vector_type(4)));

// prep: cnorm fp32, codes -> fp16 copy, codes -> fp32 transpose, zero counters
__global__ __launch_bounds__(256)
void prep(const float* __restrict__ codes, float* __restrict__ cnorm,
          _Float16* __restrict__ codes_h, float* __restrict__ codes_t,
          int* __restrict__ count1, int* __restrict__ count2) {
    if (blockIdx.x == 0 && threadIdx.x == 0) { *count1 = 0; *count2 = 0; }
    int wave = (blockIdx.x * blockDim.x + threadIdx.x) >> 6;   // 0..1023, one per code
    int lane = threadIdx.x & 63;
    float4 v = ((const float4*)(codes + (size_t)wave * D))[lane];
    // fp16 copy (k-contiguous, same layout)
    half4_t h; h[0] = (_Float16)v.x; h[1] = (_Float16)v.y; h[2] = (_Float16)v.z; h[3] = (_Float16)v.w;
    *(half4_t*)(codes_h + (size_t)wave * D + 4 * lane) = h;
    // fp32 transpose codes_t[k][c]
    codes_t[(size_t)(4*lane+0) * C + wave] = v.x;
    codes_t[(size_t)(4*lane+1) * C + wave] = v.y;
    codes_t[(size_t)(4*lane+2) * C + wave] = v.z;
    codes_t[(size_t)(4*lane+3) * C + wave] = v.w;
    float s = v.x * v.x + v.y * v.y + v.z * v.z + v.w * v.w;
    #pragma unroll
    for (int off = 32; off >= 1; off >>= 1) s += __shfl_xor(s, off, 64);
    if (lane == 0) cnorm[wave] = s;
}

// ---- main: fp16 MFMA distance argmin, 128 rows/block, all 1024 codes ----
#define LDA 264   // fp16 leading dim of x-tile (pad 8 halves)
__global__ __launch_bounds__(256, 2)
void codebook_mfma(const float* __restrict__ x, const _Float16* __restrict__ codes_h,
                   const float* __restrict__ codes, const float* __restrict__ cnorm,
                   float* __restrict__ out_q, float* __restrict__ out_i,
                   int* __restrict__ count1, int* __restrict__ rowlist1) {
    __shared__ __align__(16) char smem[128 * LDA * 2];   // 67584 B: Ah, later reduction scratch
    __shared__ int win[128];
    _Float16* Ah = (_Float16*)smem;

    const int tid  = threadIdx.x;
    const int wave = tid >> 6, lane = tid & 63;
    const int wy = wave >> 1, wx = wave & 1;
    const int quad = lane >> 4, l15 = lane & 15;
    const int row0 = blockIdx.x * 128;

    // stage x-tile fp32 -> fp16 LDS [128][LDA]
    #pragma unroll
    for (int p = 0; p < 32; ++p) {
        int flat = p * 256 + tid;          // 0..8191
        int r = flat >> 6, q = flat & 63;  // row, float4-idx
        float4 v = ((const float4*)x)[(size_t)(row0 + r) * 64 + q];
        half4_t h; h[0]=(_Float16)v.x; h[1]=(_Float16)v.y; h[2]=(_Float16)v.z; h[3]=(_Float16)v.w;
        *(half4_t*)(Ah + (size_t)r * LDA + 4 * q) = h;
    }
    __syncthreads();

    // per-lane top-2 over 16 rows (ra*4+reg); row = wy*64 + ra*16 + quad*4 + reg
    float M1[16], M2[16];
    int   I1[16];
    #pragma unroll
    for (int i = 0; i < 16; ++i) { M1[i] = FLT_MAX; M2[i] = FLT_MAX; I1[i] = 0; }

    for (int ct = 0; ct < 8; ++ct) {
        v4f acc[4][4];
        #pragma unroll
        for (int ra = 0; ra < 4; ++ra)
            #pragma unroll
            for (int jb = 0; jb < 4; ++jb)
                acc[ra][jb] = (v4f){0.f, 0.f, 0.f, 0.f};

        const _Float16* bbase = codes_h + (size_t)(ct*128 + wx*64 + l15) * D + quad*8;
        #pragma unroll
        for (int kc = 0; kc < 8; ++kc) {
            half8 bf[4], af[4];
            #pragma unroll
            for (int jb = 0; jb < 4; ++jb)
                bf[jb] = *(const half8*)(bbase + jb * (16 * D) + kc * 32);
            #pragma unroll
            for (int ra = 0; ra < 4; ++ra)
                af[ra] = *(const half8*)(Ah + (size_t)(wy*64 + ra*16 + l15) * LDA + kc*32 + quad*8);
            #pragma unroll
            for (int ra = 0; ra < 4; ++ra)
                #pragma unroll
                for (int jb = 0; jb < 4; ++jb)
                    acc[ra][jb] = __builtin_amdgcn_mfma_f32_16x16x32_f16(af[ra], bf[jb], acc[ra][jb], 0, 0, 0);
        }

        // score = cnorm - 2*dot; update per-row top-2
        float cnf[4]; int colc[4];
        #pragma unroll
        for (int jb = 0; jb < 4; ++jb) {
            colc[jb] = ct*128 + wx*64 + jb*16 + l15;
            cnf[jb]  = cnorm[colc[jb]];
        }
        #pragma unroll
        for (int ra = 0; ra < 4; ++ra)
            #pragma unroll
            for (int reg = 0; reg < 4; ++reg) {
                const int m = ra * 4 + reg;
                #pragma unroll
                for (int jb = 0; jb < 4; ++jb) {
                    float s = fmaf(-2.0f, acc[ra][jb][reg], cnf[jb]);
                    bool c = s < M1[m];
                    M2[m] = c ? M1[m] : fminf(M2[m], s);
                    M1[m] = fminf(M1[m], s);
                    I1[m] = c ? colc[jb] : I1[m];
                }
            }
    }

    // reduction: reuse Ah as scratch [128 rows][32 slots]
    __syncthreads();
    float* sm1 = (float*)smem;          // 128*32
    float* sm2 = sm1 + 4096;
    int*   sidx = (int*)(sm2 + 4096);   // total 48 KB <= 66 KB
    const int slot = wx * 16 + l15;
    #pragma unroll
    for (int ra = 0; ra < 4; ++ra)
        #pragma unroll
        for (int reg = 0; reg < 4; ++reg) {
            const int r = wy*64 + ra*16 + quad*4 + reg;
            const int m = ra*4 + reg;
            sm1[r*32 + slot] = M1[m];
            sm2[r*32 + slot] = M2[m];
            sidx[r*32 + slot] = I1[m];
        }
    __syncthreads();
    if (tid < 128) {
        float b1 = FLT_MAX, b2 = FLT_MAX;
        int bi = 0x7fffffff;
        #pragma unroll 4
        for (int t = 0; t < 32; ++t) {
            float v1 = sm1[tid*32 + t], v2 = sm2[tid*32 + t];
            int ii = sidx[tid*32 + t];
            if (v1 < b1 || (v1 == b1 && ii < bi)) { b2 = fminf(b1, v2); b1 = v1; bi = ii; }
            else b2 = fminf(b2, v1);
        }
        win[tid] = bi;
        out_i[row0 + tid] = (float)bi;
        if (b2 - b1 < EPS1) {
            int s = atomicAdd(count1, 1);
            rowlist1[s] = row0 + tid;
        }
    }
    __syncthreads();

    // gather quantized rows (flagged rows overwritten by rescues later)
    #pragma unroll
    for (int p = 0; p < 32; ++p) {
        int flat = p * 256 + tid;
        int r = flat >> 6, q = flat & 63;
        float4 v = ((const float4*)codes)[(size_t)win[r] * 64 + q];
        ((float4*)out_q)[(size_t)(row0 + r) * 64 + q] = v;
    }
}

// ---- tier-1: fp32 rescore of flagged rows, BR rows/block share codes stream ----
__global__ __launch_bounds__(256)
void rescue32(const float* __restrict__ x, const float* __restrict__ codes,
              const float* __restrict__ codes_t, const float* __restrict__ cnorm,
              const int* __restrict__ count1, const int* __restrict__ rowlist1,
              float* __restrict__ out_q, float* __restrict__ out_i,
              int* __restrict__ count2, int* __restrict__ rowlist2) {
    __shared__ __align__(16) float xr[BR * D];   // 16 KB
    __shared__ int rows_s[BR];
    __shared__ int winc_s[BR];
    __shared__ float wm1[4], wm2[4];
    __shared__ int wi_[4];
    const int t = threadIdx.x;
    const int n1 = *count1;
    if (n1 == 0) return;
    const int nb = (n1 + BR - 1) / BR;
    const float4* ct4 = (const float4*)codes_t;  // [k][c/4]

    for (int b = blockIdx.x; b < nb; b += gridDim.x) {
        __syncthreads();
        if (t < BR) {
            int idx = b * BR + t;
            if (idx >= n1) idx = n1 - 1;           // duplicate tail rows (benign)
            rows_s[t] = rowlist1[idx];
        }
        __syncthreads();
        #pragma unroll
        for (int p = 0; p < BR * 64 / 256; ++p) {  // 4 iters
            int flat = p * 256 + t;
            int r = flat >> 6, q = flat & 63;
            ((float4*)xr)[r * 64 + q] = ((const float4*)x)[(size_t)rows_s[r] * 64 + q];
        }
        __syncthreads();

        float acc[BR][4];
        #pragma unroll
        for (int r = 0; r < BR; ++r)
            #pragma unroll
            for (int j = 0; j < 4; ++j) acc[r][j] = 0.f;

        for (int k = 0; k < D; k += 4) {
            float4 cv0 = ct4[(size_t)(k+0) * 256 + t];
            float4 cv1 = ct4[(size_t)(k+1) * 256 + t];
            float4 cv2 = ct4[(size_t)(k+2) * 256 + t];
            float4 cv3 = ct4[(size_t)(k+3) * 256 + t];
            #pragma unroll
            for (int r = 0; r < BR; ++r) {
                float4 xv = *(const float4*)&xr[r * D + k];
                acc[r][0] = fmaf(xv.x, cv0.x, acc[r][0]);
                acc[r][1] = fmaf(xv.x, cv0.y, acc[r][1]);
                acc[r][2] = fmaf(xv.x, cv0.z, acc[r][2]);
                acc[r][3] = fmaf(xv.x, cv0.w, acc[r][3]);
                acc[r][0] = fmaf(xv.y, cv1.x, acc[r][0]);
                acc[r][1] = fmaf(xv.y, cv1.y, acc[r][1]);
                acc[r][2] = fmaf(xv.y, cv1.z, acc[r][2]);
                acc[r][3] = fmaf(xv.y, cv1.w, acc[r][3]);
                acc[r][0] = fmaf(xv.z, cv2.x, acc[r][0]);
                acc[r][1] = fmaf(xv.z, cv2.y, acc[r][1]);
                acc[r][2] = fmaf(xv.z, cv2.z, acc[r][2]);
                acc[r][3] = fmaf(xv.z, cv2.w, acc[r][3]);
                acc[r][0] = fmaf(xv.w, cv3.x, acc[r][0]);
                acc[r][1] = fmaf(xv.w, cv3.y, acc[r][1]);
                acc[r][2] = fmaf(xv.w, cv3.z, acc[r][2]);
                acc[r][3] = fmaf(xv.w, cv3.w, acc[r][3]);
            }
        }

        float cn0 = cnorm[4*t+0], cn1 = cnorm[4*t+1], cn2 = cnorm[4*t+2], cn3 = cnorm[4*t+3];
        for (int r = 0; r < BR; ++r) {
            float s0 = fmaf(-2.f, acc[r][0], cn0);
            float s1 = fmaf(-2.f, acc[r][1], cn1);
            float s2 = fmaf(-2.f, acc[r][2], cn2);
            float s3 = fmaf(-2.f, acc[r][3], cn3);
            float lm1 = s0; int li = 4*t;
            float lm2 = FLT_MAX;
            if (s1 < lm1) { lm2 = lm1; lm1 = s1; li = 4*t+1; } else lm2 = s1;
            if (s2 < lm1) { lm2 = lm1; lm1 = s2; li = 4*t+2; } else lm2 = fminf(lm2, s2);
            if (s3 < lm1) { lm2 = lm1; lm1 = s3; li = 4*t+3; } else lm2 = fminf(lm2, s3);
            // wave-wide butterfly merge (64 lanes all hold candidates of row r)
            #pragma unroll
            for (int off = 1; off < 64; off <<= 1) {
                float o1 = __shfl_xor(lm1, off, 64);
                float o2 = __shfl_xor(lm2, off, 64);
                int   oi = __shfl_xor(li,  off, 64);
                if (o1 < lm1 || (o1 == lm1 && oi < li)) { lm2 = fminf(lm1, o2); lm1 = o1; li = oi; }
                else lm2 = fminf(lm2, o1);
            }
            // cross-wave (4 waves) via LDS: wave w writes slot, then merge by t==0
            const int w = t >> 6;
            if ((t & 63) == 0) { wm1[w] = lm1; wm2[w] = lm2; wi_[w] = li; }
            __syncthreads();
            if (t == 0) {
                float b1 = wm1[0], b2 = wm2[0]; int bi = wi_[0];
                #pragma unroll
                for (int ww = 1; ww < 4; ++ww) {
                    float o1 = wm1[ww], o2 = wm2[ww]; int oi = wi_[ww];
                    if (o1 < b1 || (o1 == b1 && oi < bi)) { b2 = fminf(b1, o2); b1 = o1; bi = oi; }
                    else b2 = fminf(b2, o1);
                }
                const int rg = rows_s[r];
                out_i[rg] = (float)bi;
                winc_s[r] = bi;
                if (b2 - b1 < EPS2) {
                    int s = atomicAdd(count2, 1);
                    rowlist2[s] = rg;
                }
            }
            __syncthreads();
        }
        // gather quantized rows
        #pragma unroll
        for (int p = 0; p < BR * 64 / 256; ++p) {
            int flat = p * 256 + t;
            int r = flat >> 6, q = flat & 63;
            float4 v = ((const float4*)codes)[(size_t)winc_s[r] * 64 + q];
            ((float4*)out_q)[(size_t)rows_s[r] * 64 + q] = v;
        }
        __syncthreads();
    }
}

// ---- tier-2: exact fp64 rescore; smallest index within DELTA (proven round 5) ----
__global__ __launch_bounds__(256)
void rescue_exact(const float* __restrict__ x, const float* __restrict__ codes,
                  const int* __restrict__ count, const int* __restrict__ rowlist,
                  float* __restrict__ out_q, float* __restrict__ out_i) {
    __shared__ float  xrow[D];
    __shared__ double dbuf[C];
    __shared__ double rmin[256];
    __shared__ int    ridx[256];
    const int t = threadIdx.x;
    const int n = *count;
    for (int idx = blockIdx.x; idx < n; idx += gridDim.x) {
        const int row = rowlist[idx];
        __syncthreads();
        xrow[t] = x[(size_t)row * D + t];
        __syncthreads();
        double lmin = 1e300;
        #pragma unroll
        for (int j = 0; j < 4; ++j) {
            const int c = 4 * t + j;
            const float* cp = codes + (size_t)c * D;
            double s = 0.0;
            for (int k = 0; k < D; k += 4) {
                float4 cv = *(const float4*)(cp + k);
                double d0 = (double)xrow[k+0] - (double)cv.x;
                double d1 = (double)xrow[k+1] - (double)cv.y;
                double d2 = (double)xrow[k+2] - (double)cv.z;
                double d3 = (double)xrow[k+3] - (double)cv.w;
                s += d0*d0 + d1*d1 + d2*d2 + d3*d3;
            }
            dbuf[c] = s;
            lmin = fmin(lmin, s);
        }
        rmin[t] = lmin;
        __syncthreads();
        for (int sft = 128; sft > 0; sft >>= 1) {
            if (t < sft) rmin[t] = fmin(rmin[t], rmin[t + sft]);
            __syncthreads();
        }
        const double dstar = rmin[0];
        int lidx = INT_MAX;
        #pragma unroll
        for (int j = 0; j < 4; ++j) {
            const int c = 4 * t + j;
            if (dbuf[c] < dstar + DELTA && c < lidx) lidx = c;
        }
        ridx[t] = lidx;
        __syncthreads();
        for (int sft = 128; sft > 0; sft >>= 1) {
            if (t < sft) ridx[t] = min(ridx[t], ridx[t + sft]);
            __syncthreads();
        }
        const int winc = ridx[0];
        if (t == 0) out_i[row] = (float)winc;
        if (t < 64) {
            float4 cv = ((const float4*)(codes + (size_t)winc * D))[t];
            ((float4*)(out_q + (size_t)row * D))[t] = cv;
        }
        __syncthreads();
    }
}

extern "C" void kernel_launch(void* const* d_in, const int* in_sizes, int n_in,
                              void* d_out, int out_size, void* d_ws, size_t ws_size,
                              hipStream_t stream) {
    const float* x     = (const float*)d_in[0];
    const float* codes = (const float*)d_in[1];
    const int N = in_sizes[0] / D;                 // 65536

    char* ws = (char*)d_ws;
    float*    cnorm   = (float*)ws;                       ws += C * 4;              // 4 KB
    float*    codes_t = (float*)ws;                       ws += (size_t)D * C * 4;  // 1 MB
    _Float16* codes_h = (_Float16*)ws;                    ws += (size_t)C * D * 2;  // 512 KB
    int*      count1  = (int*)ws;                         ws += 16;
    int*      count2  = (int*)ws;                         ws += 16;
    int*      rowlist1 = (int*)ws;                        ws += (size_t)N * 4;
    int*      rowlist2 = (int*)ws;

    float* out_q = (float*)d_out;
    float* out_i = out_q + (size_t)N * D;

    prep<<<C / 4, 256, 0, stream>>>(codes, cnorm, codes_h, codes_t, count1, count2);
    codebook_mfma<<<N / 128, 256, 0, stream>>>(x, codes_h, codes, cnorm,
                                               out_q, out_i, count1, rowlist1);
    rescue32<<<256, 256, 0, stream>>>(x, codes, codes_t, cnorm, count1, rowlist1,
                                      out_q, out_i, count2, rowlist2);
    rescue_exact<<<128, 256, 0, stream>>>(x, codes, count2, rowlist2, out_q, out_i);
}